// Round 2
// baseline (133.630 us; speedup 1.0000x reference)
//
#include <hip/hip_runtime.h>
#include <math.h>

// SupConLoss reduced algebraically:
//   sum(sim)      = ||sum_i x_i||^2 / T
//   sum(sim*mask) = sum_c ||S_c||^2 / T,  S_c = sum_{lab==c} x_hat_i
//   n_pos         = sum_c n_c^2
// O(N*H). Labels in [0,10). N=8192, H=768.
//
// R2: removed the 1.97M-global-atomic tail (R1: 45us class_sums, WRITE=7.4MB
// of serialized TCC atomics). Now: per-block partial -> plain coalesced store
// -> tree reduce -> scalar finalize. No global atomics anywhere.

#define NCLS 10
#define HDIM 768
#define KPL  12                    // HDIM / 64
#define CLS_FLOATS (NCLS * HDIM)   // 7680

__global__ __launch_bounds__(512) void k1_partials(
    const float* __restrict__ x, const int* __restrict__ lab,
    float* __restrict__ partials, int N, int P) {
  __shared__ float cls[CLS_FLOATS];  // 30720 B
  const int tid  = threadIdx.x;
  const int lane = tid & 63;
  const int wave = tid >> 6;
  const int wavesPerBlock = blockDim.x >> 6;

  for (int i = tid; i < CLS_FLOATS; i += blockDim.x) cls[i] = 0.0f;
  __syncthreads();

  const int nwTotal = P * wavesPerBlock;
  for (int row = blockIdx.x * wavesPerBlock + wave; row < N; row += nwTotal) {
    const float* __restrict__ xr = x + (size_t)row * HDIM;
    float v[KPL];
    float ss = 0.0f;
#pragma unroll
    for (int k = 0; k < KPL; ++k) {
      v[k] = xr[lane + 64 * k];     // wave covers 256B contiguous per instr
      ss += v[k] * v[k];
    }
#pragma unroll
    for (int off = 32; off >= 1; off >>= 1) ss += __shfl_xor(ss, off, 64);
    const float rn = 1.0f / fmaxf(sqrtf(ss), 1e-12f);   // F.normalize clamp
    const int c = lab[row];                              // wave-uniform
    float* __restrict__ dst = cls + c * HDIM;
#pragma unroll
    for (int k = 0; k < KPL; ++k) {
      // lane+64k -> 2 lanes/bank: conflict-free LDS atomics (m136)
      atomicAdd(&dst[lane + 64 * k], v[k] * rn);
    }
  }
  __syncthreads();

  // plain coalesced store of this block's partial -- no atomics
  float* __restrict__ out = partials + (size_t)blockIdx.x * CLS_FLOATS;
  for (int i = tid; i < CLS_FLOATS; i += blockDim.x) out[i] = cls[i];
}

// grid: NCLS*3 blocks; block = (class, 256-wide h chunk). Reads are 1KB
// contiguous per iteration (256 lanes x 4B), L2/L3-hot.
__global__ __launch_bounds__(256) void k2_reduce(
    const float* __restrict__ partials, float* __restrict__ csum, int P) {
  const int c = blockIdx.x / 3;
  const int chunk = blockIdx.x % 3;
  const size_t idx = (size_t)c * HDIM + chunk * 256 + threadIdx.x;
  float s0 = 0.f, s1 = 0.f, s2 = 0.f, s3 = 0.f;
  int p = 0;
  for (; p + 4 <= P; p += 4) {
    s0 += partials[(size_t)(p + 0) * CLS_FLOATS + idx];
    s1 += partials[(size_t)(p + 1) * CLS_FLOATS + idx];
    s2 += partials[(size_t)(p + 2) * CLS_FLOATS + idx];
    s3 += partials[(size_t)(p + 3) * CLS_FLOATS + idx];
  }
  for (; p < P; ++p) s0 += partials[(size_t)p * CLS_FLOATS + idx];
  csum[idx] = (s0 + s1) + (s2 + s3);
}

__global__ __launch_bounds__(512) void k3_final(
    const float* __restrict__ csum, const int* __restrict__ lab,
    float* __restrict__ out, int N) {
  __shared__ int scnt[NCLS];
  __shared__ double r0[8], r1[8];
  const int tid = threadIdx.x, lane = tid & 63, wave = tid >> 6;
  if (tid < NCLS) scnt[tid] = 0;
  __syncthreads();

  // label histogram with per-thread register counters (no atomic serialization)
  int cnt[NCLS];
#pragma unroll
  for (int c = 0; c < NCLS; ++c) cnt[c] = 0;
  for (int i = tid; i < N; i += blockDim.x) {
    const int l = lab[i];
#pragma unroll
    for (int c = 0; c < NCLS; ++c) cnt[c] += (l == c);
  }
#pragma unroll
  for (int c = 0; c < NCLS; ++c) {
    int v = cnt[c];
#pragma unroll
    for (int off = 32; off >= 1; off >>= 1) v += __shfl_xor(v, off, 64);
    if (lane == 0) atomicAdd(&scnt[c], v);  // only 8 adds per class
  }

  double masked = 0.0, total = 0.0;
  for (int h = tid; h < HDIM; h += blockDim.x) {
    double tv = 0.0;
#pragma unroll
    for (int c = 0; c < NCLS; ++c) {
      const double s = (double)csum[c * HDIM + h];
      masked += s * s;
      tv += s;
    }
    total += tv * tv;
  }
#pragma unroll
  for (int off = 32; off >= 1; off >>= 1) {
    masked += __shfl_xor(masked, off, 64);
    total  += __shfl_xor(total,  off, 64);
  }
  if (lane == 0) { r0[wave] = masked; r1[wave] = total; }
  __syncthreads();
  if (tid == 0) {
    double m = 0.0, t = 0.0;
    const int nw = blockDim.x >> 6;
    for (int w = 0; w < nw; ++w) { m += r0[w]; t += r1[w]; }
    double n_pos = 0.0;
    for (int c = 0; c < NCLS; ++c) { const double cc = scnt[c]; n_pos += cc * cc; }
    const double T = 0.07;
    const double nn = (double)N * (double)N;
    const double pos_mean = m / (T * n_pos);
    const double neg_mean = (t - m) / (T * (nn - n_pos));
    const double d = neg_mean - pos_mean;
    out[0] = (float)(fmax(d, 0.0) + log1p(exp(-fabs(d))));  // logaddexp(0,d)
  }
}

extern "C" void kernel_launch(void* const* d_in, const int* in_sizes, int n_in,
                              void* d_out, int out_size, void* d_ws, size_t ws_size,
                              hipStream_t stream) {
  const float* x = (const float*)d_in[0];
  const int* lab = (const int*)d_in[1];
  const int N = in_sizes[1];  // 8192

  // ws layout: [P * 7680 floats partials][7680 floats csum]
  size_t ws_floats = ws_size / 4;
  int P = 256;
  if ((size_t)(P + 1) * CLS_FLOATS > ws_floats) {
    P = (int)(ws_floats / CLS_FLOATS) - 1;
    if (P < 1) P = 1;  // degenerate; ws is expected to be >= 8MB
  }
  float* partials = (float*)d_ws;
  float* csum = partials + (size_t)P * CLS_FLOATS;

  k1_partials<<<P, 512, 0, stream>>>(x, lab, partials, N, P);
  k2_reduce<<<NCLS * 3, 256, 0, stream>>>(partials, csum, P);
  k3_final<<<1, 512, 0, stream>>>(csum, lab, (float*)d_out, N);
}

// Round 3
// 120.213 us; speedup vs baseline: 1.1116x; 1.1116x over previous
//
#include <hip/hip_runtime.h>
#include <math.h>

// SupConLoss reduced algebraically:
//   sum(sim)      = ||sum_i x_i||^2 / T
//   sum(sim*mask) = sum_c ||S_c||^2 / T,  S_c = sum_{lab==c} x_hat_i
//   n_pos         = sum_c n_c^2
// O(N*H). Labels in [0,10). N=8192, H=768.
//
// R3: k1 was latency-bound (450 GB/s, 8 waves/CU, serial load->shuffle->LDS
// chain per row). Now: float4 loads, 2 rows in flight per wave, 16 waves/CU.
// Class-table stored PERMUTED (slot = chunk*256 + comp*64 + lane) so ds_add
// addrs are const+lane (conflict-free); permutation is an h-bijection so the
// final h-wise sums are unaffected.

#define NCLS 10
#define HDIM 768
#define HV4  (HDIM / 4)            // 192 float4 per row
#define CLS_FLOATS (NCLS * HDIM)   // 7680
#define PSLICES 4

__global__ __launch_bounds__(512) void k1_partials(
    const float* __restrict__ x, const int* __restrict__ lab,
    float* __restrict__ partials, int N, int P) {
  __shared__ float cls[CLS_FLOATS];  // 30720 B -> 2 blocks/CU with 512 thr
  const int tid = threadIdx.x, lane = tid & 63, wave = tid >> 6;
  for (int i = tid; i < CLS_FLOATS; i += blockDim.x) cls[i] = 0.0f;
  __syncthreads();

  const int wavesPerBlock = blockDim.x >> 6;
  const int gw = blockIdx.x * wavesPerBlock + wave;
  const int totalWaves = P * wavesPerBlock;
  const float4* __restrict__ x4 = (const float4*)x;

  for (int pair = gw; 2 * pair < N; pair += totalWaves) {
    const int r0 = 2 * pair;
    const int r1 = r0 + 1;  // N even; both rows valid
    const size_t b0 = (size_t)r0 * HV4, b1 = (size_t)r1 * HV4;
    // issue all 6 dwordx4 loads (both rows) before any dependent use
    float va[12], vb[12];
    {
      float4 t0 = x4[b0 + lane], t1 = x4[b0 + 64 + lane], t2 = x4[b0 + 128 + lane];
      float4 u0 = x4[b1 + lane], u1 = x4[b1 + 64 + lane], u2 = x4[b1 + 128 + lane];
      va[0]=t0.x; va[1]=t0.y; va[2]=t0.z; va[3]=t0.w;
      va[4]=t1.x; va[5]=t1.y; va[6]=t1.z; va[7]=t1.w;
      va[8]=t2.x; va[9]=t2.y; va[10]=t2.z; va[11]=t2.w;
      vb[0]=u0.x; vb[1]=u0.y; vb[2]=u0.z; vb[3]=u0.w;
      vb[4]=u1.x; vb[5]=u1.y; vb[6]=u1.z; vb[7]=u1.w;
      vb[8]=u2.x; vb[9]=u2.y; vb[10]=u2.z; vb[11]=u2.w;
    }
    const int l0 = lab[r0], l1 = lab[r1];  // wave-uniform broadcast
    float ss0 = 0.0f, ss1 = 0.0f;
#pragma unroll
    for (int m = 0; m < 12; ++m) { ss0 += va[m] * va[m]; ss1 += vb[m] * vb[m]; }
#pragma unroll
    for (int off = 32; off >= 1; off >>= 1) {  // two chains interleave (ILP)
      ss0 += __shfl_xor(ss0, off, 64);
      ss1 += __shfl_xor(ss1, off, 64);
    }
    const float rn0 = 1.0f / fmaxf(sqrtf(ss0), 1e-12f);  // F.normalize clamp
    const float rn1 = 1.0f / fmaxf(sqrtf(ss1), 1e-12f);
    float* __restrict__ d0 = cls + l0 * HDIM;
    float* __restrict__ d1 = cls + l1 * HDIM;
#pragma unroll
    for (int m = 0; m < 12; ++m) {
      // permuted slot: (m/4)*256 + (m%4)*64 + lane  -> const+lane, no conflicts
      const int s = (m >> 2) * 256 + (m & 3) * 64 + lane;
      atomicAdd(&d0[s], va[m] * rn0);
      atomicAdd(&d1[s], vb[m] * rn1);
    }
  }
  __syncthreads();

  float* __restrict__ outp = partials + (size_t)blockIdx.x * CLS_FLOATS;
  for (int i = tid; i < CLS_FLOATS; i += blockDim.x) outp[i] = cls[i];
}

// grid = 30 * PSLICES blocks; block (chunk, slice) sums partials[p in slice]
// over its 256-wide slot chunk. Coalesced 1 KB reads, L2/L3-hot.
__global__ __launch_bounds__(256) void k2_reduce(
    const float* __restrict__ partials, float* __restrict__ csum4, int P) {
  const int nchunk = CLS_FLOATS / 256;  // 30
  const int chunk = blockIdx.x % nchunk;
  const int slice = blockIdx.x / nchunk;
  const int idx = chunk * 256 + threadIdx.x;
  const int pw = P / PSLICES;
  const int p0 = slice * pw;
  const int p1 = (slice == PSLICES - 1) ? P : p0 + pw;
  float s[8];
#pragma unroll
  for (int u = 0; u < 8; ++u) s[u] = 0.0f;
  int p = p0;
  for (; p + 8 <= p1; p += 8) {
#pragma unroll
    for (int u = 0; u < 8; ++u)
      s[u] += partials[(size_t)(p + u) * CLS_FLOATS + idx];
  }
  for (; p < p1; ++p) s[0] += partials[(size_t)p * CLS_FLOATS + idx];
  csum4[(size_t)slice * CLS_FLOATS + idx] =
      ((s[0] + s[1]) + (s[2] + s[3])) + ((s[4] + s[5]) + (s[6] + s[7]));
}

__global__ __launch_bounds__(512) void k3_final(
    const float* __restrict__ csum4, const int* __restrict__ lab,
    float* __restrict__ out, int N) {
  __shared__ int scnt[NCLS];
  __shared__ double r0s[8], r1s[8];
  const int tid = threadIdx.x, lane = tid & 63, wave = tid >> 6;
  if (tid < NCLS) scnt[tid] = 0;
  __syncthreads();

  // label histogram via register counters
  int cnt[NCLS];
#pragma unroll
  for (int c = 0; c < NCLS; ++c) cnt[c] = 0;
  for (int i = tid; i < N; i += blockDim.x) {
    const int l = lab[i];
#pragma unroll
    for (int c = 0; c < NCLS; ++c) cnt[c] += (l == c);
  }
#pragma unroll
  for (int c = 0; c < NCLS; ++c) {
    int v = cnt[c];
#pragma unroll
    for (int off = 32; off >= 1; off >>= 1) v += __shfl_xor(v, off, 64);
    if (lane == 0) atomicAdd(&scnt[c], v);
  }

  // sums over storage slots (h-permutation is a bijection -> sums identical)
  double masked = 0.0, total = 0.0;
  for (int h = tid; h < HDIM; h += blockDim.x) {
    double tv = 0.0;
#pragma unroll
    for (int c = 0; c < NCLS; ++c) {
      double sv = 0.0;
#pragma unroll
      for (int sl = 0; sl < PSLICES; ++sl)
        sv += (double)csum4[(size_t)sl * CLS_FLOATS + c * HDIM + h];
      masked += sv * sv;
      tv += sv;
    }
    total += tv * tv;
  }
#pragma unroll
  for (int off = 32; off >= 1; off >>= 1) {
    masked += __shfl_xor(masked, off, 64);
    total  += __shfl_xor(total,  off, 64);
  }
  if (lane == 0) { r0s[wave] = masked; r1s[wave] = total; }
  __syncthreads();
  if (tid == 0) {
    double m = 0.0, t = 0.0;
    const int nw = blockDim.x >> 6;
    for (int w = 0; w < nw; ++w) { m += r0s[w]; t += r1s[w]; }
    double n_pos = 0.0;
    for (int c = 0; c < NCLS; ++c) { const double cc = scnt[c]; n_pos += cc * cc; }
    const double T = 0.07;
    const double nn = (double)N * (double)N;
    const double pos_mean = m / (T * n_pos);
    const double neg_mean = (t - m) / (T * (nn - n_pos));
    const double d = neg_mean - pos_mean;
    out[0] = (float)(fmax(d, 0.0) + log1p(exp(-fabs(d))));  // logaddexp(0,d)
  }
}

extern "C" void kernel_launch(void* const* d_in, const int* in_sizes, int n_in,
                              void* d_out, int out_size, void* d_ws, size_t ws_size,
                              hipStream_t stream) {
  const float* x = (const float*)d_in[0];
  const int* lab = (const int*)d_in[1];
  const int N = in_sizes[1];  // 8192

  // ws layout: [P * 7680 floats partials][PSLICES * 7680 floats csum4]
  const size_t ws_floats = ws_size / 4;
  int P = 512;  // 2 blocks/CU, 16 waves/CU
  while (P > PSLICES && (size_t)(P + PSLICES) * CLS_FLOATS > ws_floats) P >>= 1;
  float* partials = (float*)d_ws;
  float* csum4 = partials + (size_t)P * CLS_FLOATS;

  k1_partials<<<P, 512, 0, stream>>>(x, lab, partials, N, P);
  k2_reduce<<<(CLS_FLOATS / 256) * PSLICES, 256, 0, stream>>>(partials, csum4, P);
  k3_final<<<1, 512, 0, stream>>>(csum4, lab, (float*)d_out, N);
}